// Round 10
// baseline (88.143 us; speedup 1.0000x reference)
//
#include <hip/hip_runtime.h>

// RippleLinear: out[b,o] = sum_i amp[i,o] * sin(x[b,i]*freq[i,o] + ph[i,o]) + bias0[o]
//
// R10 = MEASUREMENT ROUND. The ~26-27us kernel plateau survived falsification
// of: wave count (R6), LDS ops (R5), VALU ops (R7), L2 traffic (R9), spill
// (R8). The only never-measured quantity is v_sin_f32 throughput; back-solve
// says ~31 cyc/wave-sin in BOTH R6 and R9. This round keeps the best kernel
// (R5, 75.26us bench) VERBATIM and appends a zero-memory sin-throughput probe
// (same wave-sin count/SIMD as the real kernel: 512 sins/lane, 16 waves/CU).
// Stream-serialized => bench - 75.4 = T_probe.
//   T_probe ~7us  -> trans healthy, plateau is stalls -> attack scheduling
//   T_probe ~27us -> v_sin IS the plateau -> cut trans work structurally
//                    (packed poly / MFMA polynomial-GEMM reformulation)

constexpr int IN_F   = 256;
constexpr int OUT_F  = 256;
constexpr int BROWS  = 2048;
constexpr int BTILE  = 8;                 // batch rows per block
constexpr int ISPLIT = 8;                 // i-groups per block (one wave each)
constexpr int ICHUNK = IN_F / ISPLIT;     // 32 i per group
constexpr int OPAIRS = 64;                // o-pairs per block (= 128 o columns)

#define INV2PI 0.15915494309189535f

__global__ __launch_bounds__(OPAIRS * ISPLIT, 4) void ripple_kernel(
    const float* __restrict__ x,       // (BROWS, IN_F)
    const float* __restrict__ weight,  // (IN_F, OUT_F, 2)
    const float* __restrict__ bias,    // (IN_F+1, OUT_F)
    float* __restrict__ out)           // (BROWS, OUT_F)
{
    const int tx = threadIdx.x;           // 0..63: o-pair lane
    const int g  = threadIdx.y;           // 0..7: i-group (one wave)
    const int ob = blockIdx.x & 1;        // which o-half
    const int bb = blockIdx.x >> 1;       // row-block
    const int b0 = bb * BTILE;
    const int oc = ob * OPAIRS + tx;      // global o-pair index 0..127

    __shared__ __align__(16) float xs_t[IN_F * BTILE];  // 8 KB, xs_t[i*8+r] = x/(2pi)
    __shared__ float2 red[4][BTILE][OPAIRS];            // 16 KB reduction buffer

    // --- stage x-tile transposed + prescaled: 512 threads x float4 ---
    {
        const int t  = g * OPAIRS + tx;   // 0..511
        const int r  = t >> 6;            // row 0..7
        const int c4 = t & 63;            // float4 column
        const float4 v = ((const float4*)x)[(b0 + r) * (IN_F / 4) + c4];
        xs_t[(4 * c4 + 0) * BTILE + r] = v.x * INV2PI;
        xs_t[(4 * c4 + 1) * BTILE + r] = v.y * INV2PI;
        xs_t[(4 * c4 + 2) * BTILE + r] = v.z * INV2PI;
        xs_t[(4 * c4 + 3) * BTILE + r] = v.w * INV2PI;
    }
    __syncthreads();

    float acc0[BTILE], acc1[BTILE];
#pragma unroll
    for (int r = 0; r < BTILE; ++r) { acc0[r] = 0.0f; acc1[r] = 0.0f; }

    const float4* __restrict__ wq  = (const float4*)weight;  // (amp0,freq0,amp1,freq1)
    const float2* __restrict__ ph2 = (const float2*)bias;    // phase pairs

    const int i0 = g * ICHUNK;
#pragma unroll 4
    for (int ii = 0; ii < ICHUNK; ++ii) {
        const int i = i0 + ii;
        const float4 w = wq[i * (OUT_F / 2) + oc];           // 16B coalesced
        const float2 p = ph2[(i + 1) * (OUT_F / 2) + oc];    // 8B coalesced
        const float px = p.x * INV2PI;
        const float py = p.y * INV2PI;
        const float4 xa = *(const float4*)&xs_t[i * BTILE];      // rows 0..3
        const float4 xb = *(const float4*)&xs_t[i * BTILE + 4];  // rows 4..7
        const float xv[BTILE] = {xa.x, xa.y, xa.z, xa.w, xb.x, xb.y, xb.z, xb.w};
#pragma unroll
        for (int r = 0; r < BTILE; ++r) {
            acc0[r] += w.x * __builtin_amdgcn_sinf(fmaf(xv[r], w.y, px));
            acc1[r] += w.z * __builtin_amdgcn_sinf(fmaf(xv[r], w.w, py));
        }
    }

    // --- 3-step cross-wave tree reduction over the 8 i-groups ---
    if (g >= 4) {
#pragma unroll
        for (int r = 0; r < BTILE; ++r) red[g - 4][r][tx] = make_float2(acc0[r], acc1[r]);
    }
    __syncthreads();
    if (g < 4) {
#pragma unroll
        for (int r = 0; r < BTILE; ++r) { float2 t = red[g][r][tx]; acc0[r] += t.x; acc1[r] += t.y; }
    }
    __syncthreads();
    if (g == 2 || g == 3) {
#pragma unroll
        for (int r = 0; r < BTILE; ++r) red[g - 2][r][tx] = make_float2(acc0[r], acc1[r]);
    }
    __syncthreads();
    if (g < 2) {
#pragma unroll
        for (int r = 0; r < BTILE; ++r) { float2 t = red[g][r][tx]; acc0[r] += t.x; acc1[r] += t.y; }
    }
    __syncthreads();
    if (g == 1) {
#pragma unroll
        for (int r = 0; r < BTILE; ++r) red[0][r][tx] = make_float2(acc0[r], acc1[r]);
    }
    __syncthreads();
    if (g == 0) {
        const float2 bo = ph2[oc];   // bias row 0, this o-pair
#pragma unroll
        for (int r = 0; r < BTILE; ++r) {
            float2 t = red[0][r][tx];
            float2 v = make_float2(acc0[r] + t.x + bo.x, acc1[r] + t.y + bo.y);
            ((float2*)out)[(b0 + r) * (OUT_F / 2) + oc] = v;
        }
    }
}

// --- sin-throughput probe: 512 v_sin per lane, zero global reads. ---
// 256 blocks x 1024 thr = 16 waves/CU (4/SIMD, same as ripple_kernel).
// 8 independent sin->fma chains per lane, 64 links deep: saturates the trans
// pipe unless per-link latency > ~80 cyc. Writes 1 MB to d_ws (deterministic,
// same every call). Total wave-sins/SIMD = 2048 = identical to real kernel.
__global__ __launch_bounds__(1024) void sin_probe(float* __restrict__ ws)
{
    const int tid = blockIdx.x * blockDim.x + threadIdx.x;
    float c[8];
#pragma unroll
    for (int j = 0; j < 8; ++j)
        c[j] = (float)(threadIdx.x * 8 + j) * 1.0e-4f;
#pragma unroll 4
    for (int k = 0; k < 64; ++k) {
#pragma unroll
        for (int j = 0; j < 8; ++j)
            c[j] = __builtin_amdgcn_sinf(fmaf(c[j], 0.125f, 0.0625f));  // stays in [-1,1]
    }
    float s = 0.0f;
#pragma unroll
    for (int j = 0; j < 8; ++j) s += c[j];
    ws[tid] = s;
}

extern "C" void kernel_launch(void* const* d_in, const int* in_sizes, int n_in,
                              void* d_out, int out_size, void* d_ws, size_t ws_size,
                              hipStream_t stream) {
    const float* x      = (const float*)d_in[0];
    const float* weight = (const float*)d_in[1];
    const float* bias   = (const float*)d_in[2];
    float* out          = (float*)d_out;

    dim3 grid((BROWS / BTILE) * 2);     // 512 blocks: 256 row-blocks x 2 o-halves
    dim3 block(OPAIRS, ISPLIT);         // 512 threads = 8 waves
    ripple_kernel<<<grid, block, 0, stream>>>(x, weight, bias, out);

    // throughput probe (stream-serialized after the real kernel)
    if (ws_size >= (size_t)(256 * 1024 * sizeof(float))) {
        sin_probe<<<256, 1024, 0, stream>>>((float*)d_ws);
    }
}